// Round 2
// baseline (507.805 us; speedup 1.0000x reference)
//
#include <hip/hip_runtime.h>

// PAM module: B=4, C=512, N=4096, Cq=64.
// proj_kernel: q,k,v = W@x + b (split-bf16 MFMA). q,k transposed+split
//   [B][N][64] hi/lo; v bf16 [B][C][N].
// attn_kernel: flash attention, 32-row i-panels (grid 512 -> 2 blocks/CU),
//   8 waves, raw s_barrier + lgkm-only drains so K/V register prefetch
//   survives barriers. E in LDS as [i][j] (b128 both sides), P [i][j] bf16.

typedef float          f32x2  __attribute__((ext_vector_type(2)));
typedef float          f32x4  __attribute__((ext_vector_type(4)));
typedef short          bf16x8 __attribute__((ext_vector_type(8)));
typedef unsigned short u16x4  __attribute__((ext_vector_type(4)));

#define MFMA16(a, b, c) __builtin_amdgcn_mfma_f32_16x16x32_bf16((a), (b), (c), 0, 0, 0)

__device__ __forceinline__ unsigned short bf16_rne(float f) {
    unsigned u = __builtin_bit_cast(unsigned, f);
    u += 0x7FFFu + ((u >> 16) & 1u);
    return (unsigned short)(u >> 16);
}
__device__ __forceinline__ float bf16_f(unsigned short h) {
    unsigned u = (unsigned)h << 16;
    return __builtin_bit_cast(float, u);
}

// lgkm-only drain + raw barrier: keeps global-load prefetches (vmcnt) in
// flight across the barrier (a __syncthreads would drain vmcnt(0)).
#define BARRIER_LGKM() do {                                   \
    asm volatile("s_waitcnt lgkmcnt(0)" ::: "memory");        \
    __builtin_amdgcn_s_barrier();                             \
    asm volatile("" ::: "memory");                            \
} while (0)

constexpr int BB = 4, CCH = 512, NS = 4096;

// ---------------------------------------------------------------------------
// Projection. Grid: 512 = b(4) x n-tile(128 of 32 cols). Block: 512 thr.
// Waves w<4: q o-frag (w&3)*16 (3-term split). w>=4: same for k.
// All waves: v channels [64w, 64w+64).
// ---------------------------------------------------------------------------
__global__ __launch_bounds__(512, 4) void proj_kernel(
    const float* __restrict__ x,
    const float* __restrict__ Wq, const float* __restrict__ bq,
    const float* __restrict__ Wk, const float* __restrict__ bk,
    const float* __restrict__ Wv, const float* __restrict__ bv,
    unsigned short* __restrict__ qhi, unsigned short* __restrict__ qlo,
    unsigned short* __restrict__ khi, unsigned short* __restrict__ klo,
    unsigned short* __restrict__ vws)
{
    constexpr int XS = 40;
    const int t = threadIdx.x, lane = t & 63, w = t >> 6;
    const int l15 = lane & 15, l4 = lane >> 4;
    const int b  = blockIdx.x >> 7;
    const int n0 = (blockIdx.x & 127) * 32;
    const float* xb = x + (size_t)b * CCH * NS;

    __shared__ unsigned short xh[32][XS];
    __shared__ unsigned short xl[32][XS];

    f32x4 accv[4][2];
    f32x4 accq[2];
#pragma unroll
    for (int a = 0; a < 4; ++a)
#pragma unroll
        for (int n = 0; n < 2; ++n)
#pragma unroll
            for (int r = 0; r < 4; ++r) accv[a][n][r] = 0.f;
#pragma unroll
    for (int n = 0; n < 2; ++n)
#pragma unroll
        for (int r = 0; r < 4; ++r) accq[n][r] = 0.f;

    const float* Wqk = (w < 4) ? Wq : Wk;
    const int oq0 = (w & 3) * 16;
    const int stg_c = t >> 4;        // 0..31
    const int stg_n = (t & 15) * 2;  // 0..30

    f32x2 xv = *(const f32x2*)&xb[(size_t)stg_c * NS + n0 + stg_n]; // chunk 0

    for (int cc = 0; cc < 16; ++cc) {
        // stage current chunk (from prefetched regs), transposed, split hi/lo
#pragma unroll
        for (int u = 0; u < 2; ++u) {
            unsigned short h = bf16_rne(xv[u]);
            xh[stg_n + u][stg_c] = h;
            xl[stg_n + u][stg_c] = bf16_rne(xv[u] - bf16_f(h));
        }
        BARRIER_LGKM();

        bf16x8 bh[2], bl[2];
#pragma unroll
        for (int nf = 0; nf < 2; ++nf) {
            bh[nf] = *(const bf16x8*)&xh[nf * 16 + l15][l4 * 8];
            bl[nf] = *(const bf16x8*)&xl[nf * 16 + l15][l4 * 8];
        }
        const int c8 = cc * 32 + l4 * 8;

        // prefetch next x chunk (vmcnt stays in flight across BARRIER_LGKM)
        const int ccn = (cc + 1) & 15;
        xv = *(const f32x2*)&xb[(size_t)(ccn * 32 + stg_c) * NS + n0 + stg_n];

        // v: plain bf16
#pragma unroll
        for (int af = 0; af < 4; ++af) {
            const float* wp = &Wv[(size_t)(w * 64 + af * 16 + l15) * CCH + c8];
            f32x4 wa = *(const f32x4*)wp;
            f32x4 wb = *(const f32x4*)(wp + 4);
            bf16x8 ah;
#pragma unroll
            for (int e = 0; e < 4; ++e) {
                ah[e]     = (short)bf16_rne(wa[e]);
                ah[e + 4] = (short)bf16_rne(wb[e]);
            }
#pragma unroll
            for (int nf = 0; nf < 2; ++nf)
                accv[af][nf] = MFMA16(ah, bh[nf], accv[af][nf]);
        }

        // q or k: 3-term split
        {
            const float* wp = &Wqk[(size_t)(oq0 + l15) * CCH + c8];
            f32x4 wa = *(const f32x4*)wp;
            f32x4 wb = *(const f32x4*)(wp + 4);
            bf16x8 ah, al;
#pragma unroll
            for (int e = 0; e < 4; ++e) {
                unsigned short h = bf16_rne(wa[e]);
                ah[e] = (short)h; al[e] = (short)bf16_rne(wa[e] - bf16_f(h));
                h = bf16_rne(wb[e]);
                ah[e + 4] = (short)h; al[e + 4] = (short)bf16_rne(wb[e] - bf16_f(h));
            }
#pragma unroll
            for (int nf = 0; nf < 2; ++nf) {
                accq[nf] = MFMA16(ah, bh[nf], accq[nf]);
                accq[nf] = MFMA16(ah, bl[nf], accq[nf]);
                accq[nf] = MFMA16(al, bh[nf], accq[nf]);
            }
        }
        BARRIER_LGKM();
    }

    // ---- store v bf16 [B][C][N] ----
#pragma unroll
    for (int af = 0; af < 4; ++af) {
#pragma unroll
        for (int r = 0; r < 4; ++r) {
            const int o = w * 64 + af * 16 + l4 * 4 + r;
            const float bias = bv[o];
#pragma unroll
            for (int nf = 0; nf < 2; ++nf) {
                const int n = n0 + nf * 16 + l15;
                vws[(size_t)(b * CCH + o) * NS + n] = bf16_rne(accv[af][nf][r] + bias);
            }
        }
    }

    // ---- store q/k transposed + split ----
    {
        unsigned short* hiT = (w < 4) ? qhi : khi;
        unsigned short* loT = (w < 4) ? qlo : klo;
        const float* bqk = (w < 4) ? bq : bk;
        float bias[4];
#pragma unroll
        for (int r = 0; r < 4; ++r) bias[r] = bqk[oq0 + l4 * 4 + r];
#pragma unroll
        for (int nf = 0; nf < 2; ++nf) {
            const int n = n0 + nf * 16 + l15;
            u16x4 hv, lv;
#pragma unroll
            for (int r = 0; r < 4; ++r) {
                float val = accq[nf][r] + bias[r];
                unsigned short h = bf16_rne(val);
                hv[r] = h;
                lv[r] = bf16_rne(val - bf16_f(h));
            }
            const size_t base = ((size_t)b * NS + n) * 64 + oq0 + l4 * 4;
            *(u16x4*)&hiT[base] = hv;
            *(u16x4*)&loT[base] = lv;
        }
    }
}

// ---------------------------------------------------------------------------
// Flash attention. Grid: 512 = b(4) x i-panel(128 of 32 rows). Block: 512 thr
// = 8 waves. QK: wave w computes E frag (jf=w&3, ifr=w>>2). PV: wave w owns
// channels [64w, 64w+64), both i-frags.
// ---------------------------------------------------------------------------
__global__ __launch_bounds__(512, 4) void attn_kernel(
    const float* __restrict__ x, const float* __restrict__ gamma,
    const unsigned short* __restrict__ qhi, const unsigned short* __restrict__ qlo,
    const unsigned short* __restrict__ khi, const unsigned short* __restrict__ klo,
    const unsigned short* __restrict__ vws, float* __restrict__ out)
{
    constexpr int ES = 76; // float stride (304B rows: 16B-aligned, conflict-free)
    constexpr int PS = 72; // short stride (144B rows: 16B-aligned, conflict-free)
    const int t = threadIdx.x, lane = t & 63, w = t >> 6;
    const int l15 = lane & 15, l4 = lane >> 4;
    const int b  = blockIdx.x >> 7;
    const int i0 = (blockIdx.x & 127) * 32;

    __shared__ float Elds[32][ES];            // E tile [i][j]
    __shared__ unsigned short Plds[32][PS];   // P tile [i][j] bf16
    __shared__ float m_run[32], l_run[32], sc_lds[32];

    if (t < 32) { m_run[t] = -1e30f; l_run[t] = 0.f; }

    const int jf = w & 3, ifr_w = w >> 2;

    // persistent Q B-frags (hi/lo), i = i0 + ifr_w*16 + l15
    bf16x8 qh[2], ql[2];
#pragma unroll
    for (int ds = 0; ds < 2; ++ds) {
        const size_t base = ((size_t)b * NS + i0 + ifr_w * 16 + l15) * 64 + ds * 32 + l4 * 8;
        qh[ds] = *(const bf16x8*)&qhi[base];
        ql[ds] = *(const bf16x8*)&qlo[base];
    }

    f32x4 O[4][2]; // [af(c)][ifr(i)]
#pragma unroll
    for (int a = 0; a < 4; ++a)
#pragma unroll
        for (int f = 0; f < 2; ++f)
#pragma unroll
            for (int r = 0; r < 4; ++r) O[a][f][r] = 0.f;

    const unsigned short* vb = vws + (size_t)b * CCH * NS;
    const size_t kbase = (size_t)b * NS * 64;

    // prologue prefetch: K(0), V(0)
    bf16x8 kh[2], kl[2];
    {
        const size_t kr = kbase + (size_t)(jf * 16 + l15) * 64 + l4 * 8;
        kh[0] = *(const bf16x8*)&khi[kr];      kh[1] = *(const bf16x8*)&khi[kr + 32];
        kl[0] = *(const bf16x8*)&klo[kr];      kl[1] = *(const bf16x8*)&klo[kr + 32];
    }
    bf16x8 vr[2][4]; // [js][af]
#pragma unroll
    for (int js = 0; js < 2; ++js)
#pragma unroll
        for (int af = 0; af < 4; ++af)
            vr[js][af] = *(const bf16x8*)&vb[(size_t)(w * 64 + af * 16 + l15) * NS + js * 32 + l4 * 8];

    BARRIER_LGKM(); // m_run/l_run init visible

    for (int jt = 0; jt < 64; ++jt) {
        const int jn0 = ((jt + 1) & 63) * 64;

        // ---- phase 1: E frag (3-term split), write as [i][j] b128 ----
        f32x4 eacc = {0.f, 0.f, 0.f, 0.f};
#pragma unroll
        for (int ds = 0; ds < 2; ++ds) {
            eacc = MFMA16(kh[ds], qh[ds], eacc);
            eacc = MFMA16(kh[ds], ql[ds], eacc);
            eacc = MFMA16(kl[ds], qh[ds], eacc);
        }
        // prefetch K(jt+1) (in flight across both barriers)
        {
            const size_t kr = kbase + (size_t)(jn0 + jf * 16 + l15) * 64 + l4 * 8;
            kh[0] = *(const bf16x8*)&khi[kr];  kh[1] = *(const bf16x8*)&khi[kr + 32];
            kl[0] = *(const bf16x8*)&klo[kr];  kl[1] = *(const bf16x8*)&klo[kr + 32];
        }
        *(f32x4*)&Elds[ifr_w * 16 + l15][jf * 16 + l4 * 4] = eacc;
        BARRIER_LGKM();

        // ---- phase 2: online softmax (16 lanes per row, 4 elems each) ----
        {
            const int row = t >> 4, jc = t & 15;
            f32x4 ev = *(const f32x4*)&Elds[row][jc * 4];
            float mx = fmaxf(fmaxf(ev[0], ev[1]), fmaxf(ev[2], ev[3]));
            mx = fmaxf(mx, __shfl_xor(mx, 1));
            mx = fmaxf(mx, __shfl_xor(mx, 2));
            mx = fmaxf(mx, __shfl_xor(mx, 4));
            mx = fmaxf(mx, __shfl_xor(mx, 8));
            const float m_old = m_run[row];
            const float m_new = fmaxf(m_old, mx);
            float s = 0.f;
            u16x4 pv;
#pragma unroll
            for (int e = 0; e < 4; ++e) {
                float p = __expf(ev[e] - m_new);
                s += p;
                pv[e] = bf16_rne(p);
            }
            s += __shfl_xor(s, 1);
            s += __shfl_xor(s, 2);
            s += __shfl_xor(s, 4);
            s += __shfl_xor(s, 8);
            if (jc == 0) {
                const float sc = __expf(m_old - m_new);
                l_run[row] = l_run[row] * sc + s;
                m_run[row] = m_new;
                sc_lds[row] = sc;
            }
            *(u16x4*)&Plds[row][jc * 4] = pv;
        }
        BARRIER_LGKM();

        // ---- phase 3: rescale O (skip if all sc==1), PV, prefetch V(jt+1) ----
        {
            const float sc0 = sc_lds[l15];
            const float sc1 = sc_lds[16 + l15];
            if (__any((sc0 != 1.f) || (sc1 != 1.f))) {
#pragma unroll
                for (int a = 0; a < 4; ++a)
#pragma unroll
                    for (int r = 0; r < 4; ++r) {
                        O[a][0][r] *= sc0;
                        O[a][1][r] *= sc1;
                    }
            }
            bf16x8 pb[2][2]; // [js][ifr]
#pragma unroll
            for (int js = 0; js < 2; ++js)
#pragma unroll
                for (int f = 0; f < 2; ++f)
                    pb[js][f] = *(const bf16x8*)&Plds[f * 16 + l15][js * 32 + l4 * 8];

            __builtin_amdgcn_s_setprio(1);
#pragma unroll
            for (int js = 0; js < 2; ++js)
#pragma unroll
                for (int a = 0; a < 4; ++a) {
                    O[a][0] = MFMA16(vr[js][a], pb[js][0], O[a][0]);
                    O[a][1] = MFMA16(vr[js][a], pb[js][1], O[a][1]);
                }
            __builtin_amdgcn_s_setprio(0);

            // prefetch V(jt+1)
#pragma unroll
            for (int js = 0; js < 2; ++js)
#pragma unroll
                for (int af = 0; af < 4; ++af)
                    vr[js][af] = *(const bf16x8*)&vb[(size_t)(w * 64 + af * 16 + l15) * NS + jn0 + js * 32 + l4 * 8];
        }
    }

    // ---- epilogue: out = gamma * O/l + x ----
    const float g = gamma[0];
    const float* xb = x + (size_t)b * CCH * NS;
    float linv[2];
    linv[0] = 1.f / l_run[l15];
    linv[1] = 1.f / l_run[16 + l15];
#pragma unroll
    for (int a = 0; a < 4; ++a) {
#pragma unroll
        for (int r = 0; r < 4; ++r) {
            const int c = w * 64 + a * 16 + l4 * 4 + r;
#pragma unroll
            for (int f = 0; f < 2; ++f) {
                const int i = i0 + f * 16 + l15;
                out[(size_t)(b * CCH + c) * NS + i] =
                    g * (O[a][f][r] * linv[f]) + xb[(size_t)c * NS + i];
            }
        }
    }
}

// ---------------------------------------------------------------------------
extern "C" void kernel_launch(void* const* d_in, const int* in_sizes, int n_in,
                              void* d_out, int out_size, void* d_ws, size_t ws_size,
                              hipStream_t stream)
{
    const float* x     = (const float*)d_in[0];
    const float* Wq    = (const float*)d_in[1];
    const float* bq    = (const float*)d_in[2];
    const float* Wk    = (const float*)d_in[3];
    const float* bk    = (const float*)d_in[4];
    const float* Wv    = (const float*)d_in[5];
    const float* bv    = (const float*)d_in[6];
    const float* gamma = (const float*)d_in[7];
    float* out = (float*)d_out;

    const size_t QK_ELEMS = (size_t)BB * NS * 64; // 1,048,576
    unsigned short* qhi = (unsigned short*)d_ws;
    unsigned short* qlo = qhi + QK_ELEMS;
    unsigned short* khi = qlo + QK_ELEMS;
    unsigned short* klo = khi + QK_ELEMS;
    unsigned short* v   = klo + QK_ELEMS;

    proj_kernel<<<512, 512, 0, stream>>>(x, Wq, bq, Wk, bk, Wv, bv,
                                         qhi, qlo, khi, klo, v);
    attn_kernel<<<512, 512, 0, stream>>>(x, gamma, qhi, qlo, khi, klo, v, out);
}

// Round 3
// 229.613 us; speedup vs baseline: 2.2116x; 2.2116x over previous
//
#include <hip/hip_runtime.h>

// PAM module: B=4, C=512, N=4096, Cq=64.
// prep_kernel: W -> bf16 (Wq/Wk split hi/lo) once.
// proj_kernel: q,k,v = W@x + b (split-bf16 MFMA). q,k transposed+split
//   [B][N][64] hi/lo bf16; v bf16 [B][C][N].
// attn_kernel: flash attention. 64-row i-panels (grid 256), 8 waves, j-tile
//   128 (32 iters, 2 barriers each). Q in XOR-swizzled LDS; E/P XOR-swizzled
//   LDS (conflict-free b128). K/V register-prefetched 1 tile ahead across
//   lgkm-only barriers. Register budget hand-counted ~215 <= 256 (512,2).

typedef float          f32x4  __attribute__((ext_vector_type(4)));
typedef short          bf16x8 __attribute__((ext_vector_type(8)));
typedef unsigned short u16x4  __attribute__((ext_vector_type(4)));
typedef unsigned short u16x8  __attribute__((ext_vector_type(8)));

#define MFMA16(a, b, c) __builtin_amdgcn_mfma_f32_16x16x32_bf16((a), (b), (c), 0, 0, 0)

__device__ __forceinline__ unsigned short bf16_rne(float f) {
    unsigned u = __builtin_bit_cast(unsigned, f);
    u += 0x7FFFu + ((u >> 16) & 1u);
    return (unsigned short)(u >> 16);
}
__device__ __forceinline__ float bf16_f(unsigned short h) {
    unsigned u = (unsigned)h << 16;
    return __builtin_bit_cast(float, u);
}

// lgkm-only drain + raw barrier: keeps global-load prefetches (vmcnt) in
// flight across the barrier (a __syncthreads would drain vmcnt(0)).
#define BARRIER_LGKM() do {                                   \
    asm volatile("s_waitcnt lgkmcnt(0)" ::: "memory");        \
    __builtin_amdgcn_s_barrier();                             \
    asm volatile("" ::: "memory");                            \
} while (0)

constexpr int BB = 4, CCH = 512, NS = 4096;

// ---------------------------------------------------------------------------
// Prep: convert weights to bf16. Grid 256 x 256 threads.
// ---------------------------------------------------------------------------
__global__ void prep_kernel(
    const float* __restrict__ Wq, const float* __restrict__ Wk,
    const float* __restrict__ Wv,
    unsigned short* __restrict__ Wqh, unsigned short* __restrict__ Wql,
    unsigned short* __restrict__ Wkh, unsigned short* __restrict__ Wkl,
    unsigned short* __restrict__ Wvb)
{
    const int idx = blockIdx.x * 256 + threadIdx.x; // 0..65535
    {
        f32x4 v = *(const f32x4*)&Wv[(size_t)idx * 4];
        u16x4 o;
#pragma unroll
        for (int e = 0; e < 4; ++e) o[e] = bf16_rne(v[e]);
        *(u16x4*)&Wvb[(size_t)idx * 4] = o;
    }
    if (idx < 8192) {
        f32x4 q = *(const f32x4*)&Wq[(size_t)idx * 4];
        f32x4 k = *(const f32x4*)&Wk[(size_t)idx * 4];
        u16x4 qh, ql, kh, kl;
#pragma unroll
        for (int e = 0; e < 4; ++e) {
            unsigned short h = bf16_rne(q[e]);
            qh[e] = h; ql[e] = bf16_rne(q[e] - bf16_f(h));
            h = bf16_rne(k[e]);
            kh[e] = h; kl[e] = bf16_rne(k[e] - bf16_f(h));
        }
        *(u16x4*)&Wqh[(size_t)idx * 4] = qh;
        *(u16x4*)&Wql[(size_t)idx * 4] = ql;
        *(u16x4*)&Wkh[(size_t)idx * 4] = kh;
        *(u16x4*)&Wkl[(size_t)idx * 4] = kl;
    }
}

// ---------------------------------------------------------------------------
// Projection. Grid: 256 = b(4) x n-tile(64 of 64 cols). Block: 512 thr.
// Waves w<4: q o-frag (w&3)*16 (3-term split). w>=4: same for k.
// All waves: v channels [64w, 64w+64).
// ---------------------------------------------------------------------------
__global__ __launch_bounds__(512, 2) void proj_kernel(
    const float* __restrict__ x,
    const unsigned short* __restrict__ Wqh, const unsigned short* __restrict__ Wql,
    const unsigned short* __restrict__ Wkh, const unsigned short* __restrict__ Wkl,
    const unsigned short* __restrict__ Wvb,
    const float* __restrict__ bq, const float* __restrict__ bk,
    const float* __restrict__ bv,
    unsigned short* __restrict__ qhi, unsigned short* __restrict__ qlo,
    unsigned short* __restrict__ khi, unsigned short* __restrict__ klo,
    unsigned short* __restrict__ vws)
{
    const int t = threadIdx.x, lane = t & 63, w = t >> 6;
    const int l15 = lane & 15, l4 = lane >> 4;
    const int b  = blockIdx.x >> 6;
    const int n0 = (blockIdx.x & 63) * 64;
    const float* xb = x + (size_t)b * CCH * NS;

    __shared__ unsigned short xh[64][40]; // x tile transposed [n][c] hi
    __shared__ unsigned short xl[64][40]; // lo

    f32x4 accv[4][4]; // [af][nf]
    f32x4 accq[4];    // [nf]
#pragma unroll
    for (int a = 0; a < 4; ++a)
#pragma unroll
        for (int n = 0; n < 4; ++n)
#pragma unroll
            for (int r = 0; r < 4; ++r) accv[a][n][r] = 0.f;
#pragma unroll
    for (int n = 0; n < 4; ++n)
#pragma unroll
        for (int r = 0; r < 4; ++r) accq[n][r] = 0.f;

    const unsigned short* Wh = (w < 4) ? Wqh : Wkh;
    const unsigned short* Wl = (w < 4) ? Wql : Wkl;
    const int oq0 = (w & 3) * 16;
    const int stg_c = t >> 4;        // 0..31
    const int stg_n = (t & 15) * 4;  // 0..60

    f32x4 xv = *(const f32x4*)&xb[(size_t)stg_c * NS + n0 + stg_n]; // chunk 0

    for (int cc = 0; cc < 16; ++cc) {
        // stage current chunk (from prefetched regs), transposed, split hi/lo
#pragma unroll
        for (int u = 0; u < 4; ++u) {
            unsigned short h = bf16_rne(xv[u]);
            xh[stg_n + u][stg_c] = h;
            xl[stg_n + u][stg_c] = bf16_rne(xv[u] - bf16_f(h));
        }
        BARRIER_LGKM();

        bf16x8 bh[4], bl[4];
#pragma unroll
        for (int nf = 0; nf < 4; ++nf) {
            bh[nf] = *(const bf16x8*)&xh[nf * 16 + l15][l4 * 8];
            bl[nf] = *(const bf16x8*)&xl[nf * 16 + l15][l4 * 8];
        }
        const int c8 = cc * 32 + l4 * 8;

        // prefetch next x chunk (vmcnt stays in flight across BARRIER_LGKM)
        const int ccn = (cc + 1) & 15;
        xv = *(const f32x4*)&xb[(size_t)(ccn * 32 + stg_c) * NS + n0 + stg_n];

        // v: plain bf16
#pragma unroll
        for (int af = 0; af < 4; ++af) {
            bf16x8 ah = *(const bf16x8*)&Wvb[(size_t)(w * 64 + af * 16 + l15) * CCH + c8];
#pragma unroll
            for (int nf = 0; nf < 4; ++nf)
                accv[af][nf] = MFMA16(ah, bh[nf], accv[af][nf]);
        }
        // q or k: 3-term split
        {
            bf16x8 ah = *(const bf16x8*)&Wh[(size_t)(oq0 + l15) * CCH + c8];
            bf16x8 al = *(const bf16x8*)&Wl[(size_t)(oq0 + l15) * CCH + c8];
#pragma unroll
            for (int nf = 0; nf < 4; ++nf) {
                accq[nf] = MFMA16(ah, bh[nf], accq[nf]);
                accq[nf] = MFMA16(ah, bl[nf], accq[nf]);
                accq[nf] = MFMA16(al, bh[nf], accq[nf]);
            }
        }
        BARRIER_LGKM();
    }

    // ---- store v bf16 [B][C][N] ----
#pragma unroll
    for (int af = 0; af < 4; ++af) {
#pragma unroll
        for (int r = 0; r < 4; ++r) {
            const int o = w * 64 + af * 16 + l4 * 4 + r;
            const float bias = bv[o];
#pragma unroll
            for (int nf = 0; nf < 4; ++nf) {
                const int n = n0 + nf * 16 + l15;
                vws[(size_t)(b * CCH + o) * NS + n] = bf16_rne(accv[af][nf][r] + bias);
            }
        }
    }

    // ---- store q/k transposed + split: [B][N][64] hi & lo ----
    {
        unsigned short* hiT = (w < 4) ? qhi : khi;
        unsigned short* loT = (w < 4) ? qlo : klo;
        const float* bqk = (w < 4) ? bq : bk;
        float bias[4];
#pragma unroll
        for (int r = 0; r < 4; ++r) bias[r] = bqk[oq0 + l4 * 4 + r];
#pragma unroll
        for (int nf = 0; nf < 4; ++nf) {
            const int n = n0 + nf * 16 + l15;
            u16x4 hv, lv;
#pragma unroll
            for (int r = 0; r < 4; ++r) {
                float val = accq[nf][r] + bias[r];
                unsigned short h = bf16_rne(val);
                hv[r] = h;
                lv[r] = bf16_rne(val - bf16_f(h));
            }
            const size_t base = ((size_t)b * NS + n) * 64 + oq0 + l4 * 4;
            *(u16x4*)&hiT[base] = hv;
            *(u16x4*)&loT[base] = lv;
        }
    }
}

// ---------------------------------------------------------------------------
// Flash attention. Grid: 256 = b(4) x i-panel(64 of 64 rows). Block: 512 thr
// = 8 waves. j-tile 128 (32 iterations). QK: wave w computes jf=w for all 4
// i-frags. PV: wave w owns channels [64w, 64w+64), all 4 i-frags.
// ---------------------------------------------------------------------------
__global__ __launch_bounds__(512, 2) void attn_kernel(
    const float* __restrict__ x, const float* __restrict__ gamma,
    const unsigned short* __restrict__ qhi, const unsigned short* __restrict__ qlo,
    const unsigned short* __restrict__ khi, const unsigned short* __restrict__ klo,
    const unsigned short* __restrict__ vws, float* __restrict__ out)
{
    const int t = threadIdx.x, lane = t & 63, w = t >> 6;
    const int l15 = lane & 15, l4 = lane >> 4;
    const int b  = blockIdx.x >> 6;
    const int i0 = (blockIdx.x & 63) * 64;

    // XOR-swizzled LDS (all b128 accesses bank-uniform, no padding):
    //   Qlds[h][i][ (g ^ (i&7))*8 + d7 ],  g = d/8   (0..7)
    //   Elds[i]   [ (g ^ (i&7))*4 + e  ],  g = j/4   (0..31, low-3-bit XOR)
    //   Plds[i]   [ (g ^ (i&15))*8 + j7],  g = j/8   (0..15)
    __shared__ unsigned short Qlds[2][64][64];
    __shared__ float          Elds[64][128];
    __shared__ unsigned short Plds[64][128];
    __shared__ float m_run[64], l_run[64], sc_lds[64];

    // ---- prologue: stage Q into LDS (swizzled) ----
    {
        const int qi = t >> 3, g0 = t & 7;
        const size_t ga = ((size_t)(b * NS + i0 + qi)) * 64 + g0 * 8;
        bf16x8 qh8 = *(const bf16x8*)&qhi[ga];
        bf16x8 ql8 = *(const bf16x8*)&qlo[ga];
        const int gs = ((g0 ^ (qi & 7)) * 8);
        *(bf16x8*)&Qlds[0][qi][gs] = qh8;
        *(bf16x8*)&Qlds[1][qi][gs] = ql8;
    }
    if (t < 64) { m_run[t] = -1e30f; l_run[t] = 0.f; }

    f32x4 O[4][4]; // [af(c)][if(i)]
#pragma unroll
    for (int a = 0; a < 4; ++a)
#pragma unroll
        for (int f = 0; f < 4; ++f)
#pragma unroll
            for (int r = 0; r < 4; ++r) O[a][f][r] = 0.f;

    const unsigned short* vb = vws + (size_t)b * CCH * NS;
    const size_t kbase = (size_t)b * NS * 64;

    // prologue prefetch: K(0) frags (jf=w), V(0) frags
    bf16x8 kh[2], kl[2];
    {
        const size_t kr = kbase + (size_t)(w * 16 + l15) * 64 + l4 * 8;
        kh[0] = *(const bf16x8*)&khi[kr];  kh[1] = *(const bf16x8*)&khi[kr + 32];
        kl[0] = *(const bf16x8*)&klo[kr];  kl[1] = *(const bf16x8*)&klo[kr + 32];
    }
    bf16x8 va[4][4]; // [js][af]
#pragma unroll
    for (int js = 0; js < 4; ++js)
#pragma unroll
        for (int af = 0; af < 4; ++af)
            va[js][af] = *(const bf16x8*)&vb[(size_t)(w * 64 + af * 16 + l15) * NS + js * 32 + l4 * 8];

    BARRIER_LGKM(); // Q staged + m/l init visible; K/V loads still in flight

    for (int jt = 0; jt < 32; ++jt) {
        const int jn = ((jt + 1) & 31) * 128; // next tile base (wraps)

        // ---- phase 1: E = K·Q^T (3-term split), 24 MFMAs/wave ----
        f32x4 eacc[4];
#pragma unroll
        for (int f = 0; f < 4; ++f)
#pragma unroll
            for (int r = 0; r < 4; ++r) eacc[f][r] = 0.f;
#pragma unroll
        for (int ds = 0; ds < 2; ++ds) {
            const int gq = ((ds * 4 + l4) ^ (l15 & 7)) * 8;
            bf16x8 qhf[4], qlf[4];
#pragma unroll
            for (int f = 0; f < 4; ++f) {
                qhf[f] = *(const bf16x8*)&Qlds[0][f * 16 + l15][gq];
                qlf[f] = *(const bf16x8*)&Qlds[1][f * 16 + l15][gq];
            }
#pragma unroll
            for (int f = 0; f < 4; ++f) {
                eacc[f] = MFMA16(kh[ds], qhf[f], eacc[f]);
                eacc[f] = MFMA16(kh[ds], qlf[f], eacc[f]);
                eacc[f] = MFMA16(kl[ds], qhf[f], eacc[f]);
            }
        }
        // prefetch K(jt+1) (stays in flight across barriers)
        {
            const size_t kr = kbase + (size_t)(jn + w * 16 + l15) * 64 + l4 * 8;
            kh[0] = *(const bf16x8*)&khi[kr];  kh[1] = *(const bf16x8*)&khi[kr + 32];
            kl[0] = *(const bf16x8*)&klo[kr];  kl[1] = *(const bf16x8*)&klo[kr + 32];
        }
        // write E frags: row i = f*16+l15, j-group g = w*4+l4
        {
            const int ge = (w * 4 + l4);
#pragma unroll
            for (int f = 0; f < 4; ++f)
                *(f32x4*)&Elds[f * 16 + l15][(ge ^ (l15 & 7)) * 4] = eacc[f];
        }
        BARRIER_LGKM();

        // ---- phase 2: online softmax (8 threads/row, 16 j each) ----
        {
            const int row = t >> 3, jc = t & 7;
            f32x4 ev[4];
#pragma unroll
            for (int s = 0; s < 4; ++s)
                ev[s] = *(const f32x4*)&Elds[row][((jc * 4 + s) ^ (row & 7)) * 4];
            float mx = -1e30f;
#pragma unroll
            for (int s = 0; s < 4; ++s)
#pragma unroll
                for (int e = 0; e < 4; ++e) mx = fmaxf(mx, ev[s][e]);
            mx = fmaxf(mx, __shfl_xor(mx, 1));
            mx = fmaxf(mx, __shfl_xor(mx, 2));
            mx = fmaxf(mx, __shfl_xor(mx, 4));
            const float m_old = m_run[row];
            const float m_new = fmaxf(m_old, mx);
            float s_sum = 0.f;
            u16x8 pv0, pv1;
#pragma unroll
            for (int s = 0; s < 4; ++s)
#pragma unroll
                for (int e = 0; e < 4; ++e) {
                    float p = __expf(ev[s][e] - m_new);
                    s_sum += p;
                    unsigned short ph = bf16_rne(p);
                    if (s < 2) pv0[s * 4 + e] = ph; else pv1[(s - 2) * 4 + e] = ph;
                }
            s_sum += __shfl_xor(s_sum, 1);
            s_sum += __shfl_xor(s_sum, 2);
            s_sum += __shfl_xor(s_sum, 4);
            if (jc == 0) {
                const float sc = __expf(m_old - m_new);
                l_run[row] = l_run[row] * sc + s_sum;
                m_run[row] = m_new;
                sc_lds[row] = sc;
            }
            *(u16x8*)&Plds[row][((2 * jc)     ^ (row & 15)) * 8] = pv0;
            *(u16x8*)&Plds[row][((2 * jc + 1) ^ (row & 15)) * 8] = pv1;
        }
        BARRIER_LGKM();

        // ---- phase 3: rescale O (skip if all sc==1), PV, prefetch V ----
        {
            float scv[4];
#pragma unroll
            for (int f = 0; f < 4; ++f) scv[f] = sc_lds[f * 16 + l15];
            if (__any((scv[0] != 1.f) || (scv[1] != 1.f) ||
                      (scv[2] != 1.f) || (scv[3] != 1.f))) {
#pragma unroll
                for (int a = 0; a < 4; ++a)
#pragma unroll
                    for (int f = 0; f < 4; ++f)
#pragma unroll
                        for (int r = 0; r < 4; ++r) O[a][f][r] *= scv[f];
            }
#pragma unroll
            for (int js = 0; js < 4; ++js) {
                bf16x8 pb[4];
#pragma unroll
                for (int f = 0; f < 4; ++f)
                    pb[f] = *(const bf16x8*)&Plds[f * 16 + l15][((js * 4 + l4) ^ l15) * 8];
#pragma unroll
                for (int a = 0; a < 4; ++a)
#pragma unroll
                    for (int f = 0; f < 4; ++f)
                        O[a][f] = MFMA16(va[js][a], pb[f], O[a][f]);
                // prefetch V(jt+1) js-slice into the regs just consumed
#pragma unroll
                for (int af = 0; af < 4; ++af)
                    va[js][af] = *(const bf16x8*)&vb[(size_t)(w * 64 + af * 16 + l15) * NS + jn + js * 32 + l4 * 8];
            }
        }
        // next Elds write is fenced by this iteration's two barriers
    }

    // ---- epilogue: out = gamma * O/l + x ----
    const float g = gamma[0];
    const float* xb = x + (size_t)b * CCH * NS;
    float linv[4];
#pragma unroll
    for (int f = 0; f < 4; ++f) linv[f] = 1.f / l_run[f * 16 + l15];
#pragma unroll
    for (int a = 0; a < 4; ++a) {
#pragma unroll
        for (int r = 0; r < 4; ++r) {
            const int c = w * 64 + a * 16 + l4 * 4 + r;
#pragma unroll
            for (int f = 0; f < 4; ++f) {
                const int i = i0 + f * 16 + l15;
                out[(size_t)(b * CCH + c) * NS + i] =
                    g * (O[a][f][r] * linv[f]) + xb[(size_t)c * NS + i];
            }
        }
    }
}

// ---------------------------------------------------------------------------
extern "C" void kernel_launch(void* const* d_in, const int* in_sizes, int n_in,
                              void* d_out, int out_size, void* d_ws, size_t ws_size,
                              hipStream_t stream)
{
    const float* x     = (const float*)d_in[0];
    const float* Wq    = (const float*)d_in[1];
    const float* bq    = (const float*)d_in[2];
    const float* Wk    = (const float*)d_in[3];
    const float* bk    = (const float*)d_in[4];
    const float* Wv    = (const float*)d_in[5];
    const float* bv    = (const float*)d_in[6];
    const float* gamma = (const float*)d_in[7];
    float* out = (float*)d_out;

    const size_t QK_ELEMS = (size_t)BB * NS * 64;   // 1,048,576
    unsigned short* qhi = (unsigned short*)d_ws;
    unsigned short* qlo = qhi + QK_ELEMS;
    unsigned short* khi = qlo + QK_ELEMS;
    unsigned short* klo = khi + QK_ELEMS;
    unsigned short* v   = klo + QK_ELEMS;           // [4][512][4096] = 16 MB
    unsigned short* Wvb = v   + (size_t)BB * CCH * NS; // 512*512
    unsigned short* Wqh = Wvb + (size_t)CCH * CCH;
    unsigned short* Wql = Wqh + 64 * CCH;
    unsigned short* Wkh = Wql + 64 * CCH;
    unsigned short* Wkl = Wkh + 64 * CCH;           // end ~24.9 MB

    prep_kernel<<<256, 256, 0, stream>>>(Wq, Wk, Wv, Wqh, Wql, Wkh, Wkl, Wvb);
    proj_kernel<<<256, 512, 0, stream>>>(x, Wqh, Wql, Wkh, Wkl, Wvb,
                                         bq, bk, bv, qhi, qlo, khi, klo, v);
    attn_kernel<<<256, 512, 0, stream>>>(x, gamma, qhi, qlo, khi, klo, v, out);
}